// Round 4
// baseline (12.481 us; speedup 1.0000x reference)
//
#include <hip/hip_runtime.h>

#define KG 16          // gaussians per row
#define PROW (7 * KG)  // 112 floats per (b, ch) row
#define PPT 8          // pixels per thread
#define BLK 256

#if defined(__has_builtin) && __has_builtin(__builtin_amdgcn_exp2f)
#define EXP2F(x) __builtin_amdgcn_exp2f(x)
#else
#define EXP2F(x) exp2f(x)
#endif
#if defined(__has_builtin) && __has_builtin(__builtin_amdgcn_rcpf)
#define RCPF(x) __builtin_amdgcn_rcpf(x)
#else
#define RCPF(x) (1.0f / (x))
#endif

// Single fused kernel. Per-block preamble (16 threads) computes, per gaussian
// k, the expanded quadratic in the log2 domain:
//   E(gx,gy) = Cxx gx^2 + Cxy gx gy + Cyy gy^2 + Cx gx + Cy gy + C0
// so e = exp2(E). Main loop walks 8 consecutive pixels (= consecutive gy at
// fixed gx, since grid[n] = (xx[n/H], yy[n%H])) via forward differencing:
//   E_{t+1} = E_t + d1,  d1_{t+1} = d1 + dd,  dd = 2 Cyy dY^2.
__global__ __launch_bounds__(BLK) void moe_fused_kernel(
    const float* __restrict__ params,
    const int* __restrict__ hptr,
    const int* __restrict__ wptr,
    float* __restrict__ out,
    int N)
{
    const int a = blockIdx.y;
    const int H = *hptr;
    const int W = *wptr;
    const float dY = 1.0f / (float)(H - 1);
    const float invW = 1.0f / (float)(W - 1);

    __shared__ float sc[KG][8];  // {Cxx,Cxy,Cyy,Cx,Cy,C0,w,dd}

    if (threadIdx.x < KG) {
        const int k = threadIdx.x;
        const float* p = params + (size_t)a * PROW;
        const float mx = p[k];
        const float my = p[KG + k];
        const float s00 = p[3 * KG + 4 * k + 0];
        const float s10 = p[3 * KG + 4 * k + 2];
        const float s11 = p[3 * KG + 4 * k + 3];
        // sigma = L L^T (L = tril); srow = row sums
        const float s0 = s00 * s00 + s00 * s10;
        const float s1 = s10 * s00 + s10 * s10 + s11 * s11;

        // softmax over K logits: lane k holds logit k, shfl-reduce over 16
        const float lk = p[2 * KG + k];
        float m = lk;
        #pragma unroll
        for (int off = 1; off < KG; off <<= 1) m = fmaxf(m, __shfl_xor(m, off, 64));
        const float ek = __expf(lk - m);
        float den = ek;
        #pragma unroll
        for (int off = 1; off < KG; off <<= 1) den += __shfl_xor(den, off, 64);
        const float wk = ek / den;

        const float Q = -0.72134752044448170368f;  // -0.5 * log2(e)
        const float sxy = s0 + s1;
        const float Cyy = Q * s1;
        sc[k][0] = Q * s0;
        sc[k][1] = Q * sxy;
        sc[k][2] = Cyy;
        sc[k][3] = Q * (-2.0f * s0 * mx - sxy * my);
        sc[k][4] = Q * (-2.0f * s1 * my - sxy * mx);
        sc[k][5] = Q * (s0 * mx * mx + sxy * mx * my + s1 * my * my);
        sc[k][6] = wk;
        sc[k][7] = 2.0f * Cyy * dY * dY;
    }
    __syncthreads();

    const int base = (blockIdx.x * BLK + threadIdx.x) * PPT;
    if (base >= N) return;

    // n/H, n%H — H is 256 in practice: use shifts when H is a power of two
    const unsigned uH = (unsigned)H;
    unsigned i0, j0;
    if ((uH & (uH - 1)) == 0) {
        const int sh = __ffs((int)uH) - 1;
        i0 = (unsigned)base >> sh;
        j0 = (unsigned)base & (uH - 1);
    } else {
        i0 = (unsigned)base / uH;
        j0 = (unsigned)base - i0 * uH;
    }
    const float gx = (float)i0 * invW;
    const float gy0 = (float)j0 * dY;

    if (base + PPT <= N && j0 + PPT <= uH) {
        // fast path: all 8 pixels share gx, consecutive gy
        const float gx2 = gx * gx;
        const float gy02 = gy0 * gy0;
        const float ty = dY * (2.0f * gy0 + dY);  // (gy0+dY)^2 - gy0^2

        float es[PPT], ws[PPT];
        #pragma unroll
        for (int t = 0; t < PPT; ++t) { es[t] = 0.0f; ws[t] = 0.0f; }

        #pragma unroll
        for (int k = 0; k < KG; ++k) {
            const float Cxx = sc[k][0], Cxy = sc[k][1], Cyy = sc[k][2];
            const float Cx = sc[k][3], Cy = sc[k][4], C0 = sc[k][5];
            const float wk = sc[k][6], dd = sc[k][7];
            const float A0x = fmaf(Cxx, gx2, fmaf(Cx, gx, C0));  // gx-only part
            const float B = fmaf(Cxy, gx, Cy);
            float E = fmaf(Cyy, gy02, fmaf(B, gy0, A0x));
            float d1 = fmaf(Cyy, ty, B * dY);
            #pragma unroll
            for (int t = 0; t < PPT; ++t) {
                const float e = EXP2F(E);
                es[t] += e;
                ws[t] = fmaf(wk, e, ws[t]);
                if (t < PPT - 1) { E += d1; d1 += dd; }
            }
        }

        float r[PPT];
        #pragma unroll
        for (int t = 0; t < PPT; ++t) {
            const float g = fmaxf(es[t], 1e-8f);
            const float y = ws[t] * RCPF(g);
            r[t] = fminf(fmaxf(y, 0.0f), 1.0f);
        }
        float4* o = reinterpret_cast<float4*>(out + (size_t)a * (size_t)N + base);
        o[0] = make_float4(r[0], r[1], r[2], r[3]);
        o[1] = make_float4(r[4], r[5], r[6], r[7]);
    } else {
        // slow path: column crossing or tail — direct eval per pixel
        for (int t = 0; t < PPT && base + t < N; ++t) {
            const unsigned n = (unsigned)(base + t);
            const unsigned it = n / uH;
            const unsigned jt = n - it * uH;
            const float x = (float)it * invW;
            const float yv = (float)jt * dY;
            float esum = 0.0f, wsum = 0.0f;
            #pragma unroll
            for (int k = 0; k < KG; ++k) {
                const float E = fmaf(sc[k][2], yv * yv,
                                fmaf(fmaf(sc[k][1], x, sc[k][4]), yv,
                                fmaf(sc[k][0], x * x, fmaf(sc[k][3], x, sc[k][5]))));
                const float e = EXP2F(E);
                esum += e;
                wsum = fmaf(sc[k][6], e, wsum);
            }
            const float y = wsum * RCPF(fmaxf(esum, 1e-8f));
            out[(size_t)a * (size_t)N + n] = fminf(fmaxf(y, 0.0f), 1.0f);
        }
    }
}

extern "C" void kernel_launch(void* const* d_in, const int* in_sizes, int n_in,
                              void* d_out, int out_size, void* d_ws, size_t ws_size,
                              hipStream_t stream) {
    const float* params = (const float*)d_in[0];
    const int* hptr = (const int*)d_in[1];
    const int* wptr = (const int*)d_in[2];
    float* out = (float*)d_out;

    const int A = in_sizes[0] / PROW;   // B*CH = 24
    const int N = out_size / A;         // H*W = 65536

    dim3 block(BLK);
    dim3 grid((N + BLK * PPT - 1) / (BLK * PPT), A);
    moe_fused_kernel<<<grid, block, 0, stream>>>(params, hptr, wptr, out, N);
}